// Round 11
// baseline (136.969 us; speedup 1.0000x reference)
//
#include <hip/hip_runtime.h>
#include <hip/hip_bf16.h>

typedef unsigned short u16;
typedef __attribute__((ext_vector_type(8))) short short8;
typedef __attribute__((ext_vector_type(4))) float f32x4;
typedef __attribute__((ext_vector_type(16))) float f32x16;
typedef __attribute__((ext_vector_type(4))) float float4v;
typedef __attribute__((ext_vector_type(4))) unsigned int uint4v;
typedef __attribute__((ext_vector_type(2))) unsigned int uint2v;

__device__ __forceinline__ u16 f2bf(float f) {
    union { float f; unsigned u; } x;
    x.f = f;
    unsigned r = x.u + 0x7fffu + ((x.u >> 16) & 1u);  // RNE
    return (u16)(r >> 16);
}

__device__ __forceinline__ unsigned cvtpk(float lo, float hi) {
    unsigned r;
    asm("v_cvt_pk_bf16_f32 %0, %1, %2" : "=v"(r) : "v"(lo), "v"(hi));
    return r;
}

__device__ __forceinline__ void gload16(const u16* g, u16* l) {
    __builtin_amdgcn_global_load_lds(
        (const __attribute__((address_space(1))) unsigned*)g,
        (__attribute__((address_space(3))) unsigned*)l, 16, 0, 0);
}

#define WAITV(n) asm volatile("s_waitcnt vmcnt(" #n ")" ::: "memory")

// ---------------- fused prep: cast x + transpose Wqkv + transpose Wo -------
__global__ __launch_bounds__(256) void prep(
    const float* __restrict__ x, const float* __restrict__ Wqkv,
    const float* __restrict__ Wo, u16* __restrict__ x_bf,
    u16* __restrict__ wqkvT, u16* __restrict__ woT) {
    int bid = blockIdx.x;
    int t = threadIdx.x;
    if (bid < 2048) {
        int i = bid * 256 + t;
        const float4v* s = (const float4v*)(x + (size_t)i * 8);
        float4v a = s[0], b = s[1];
        uint4v o;
        o[0] = (unsigned)f2bf(a[0]) | ((unsigned)f2bf(a[1]) << 16);
        o[1] = (unsigned)f2bf(a[2]) | ((unsigned)f2bf(a[3]) << 16);
        o[2] = (unsigned)f2bf(b[0]) | ((unsigned)f2bf(b[1]) << 16);
        o[3] = (unsigned)f2bf(b[2]) | ((unsigned)f2bf(b[3]) << 16);
        *(uint4v*)(x_bf + (size_t)i * 8) = o;
        return;
    }
    const float* src;
    u16* dst;
    int C, tid;
    if (bid < 2816) { tid = bid - 2048; src = Wqkv; dst = wqkvT; C = 3072; }
    else            { tid = bid - 2816; src = Wo;   dst = woT;   C = 1024; }
    int tr = (tid & 15) * 64;
    int tc = (tid >> 4) * 64;
    __shared__ __align__(16) u16 tile[64][72];
    int r = t >> 2;
    int c4 = (t & 3) * 16;
    const float4v* sp = (const float4v*)(src + (size_t)(tr + r) * C + tc + c4);
#pragma unroll
    for (int v = 0; v < 4; v++) {
        float4v xv = sp[v];
#pragma unroll
        for (int j = 0; j < 4; j++) tile[r][c4 + v * 4 + j] = f2bf(xv[j]);
    }
    __syncthreads();
    u16* dp = dst + (size_t)(tc + r) * 1024 + tr + c4;
#pragma unroll
    for (int i = 0; i < 16; i++) dp[i] = tile[c4 + i][r];
}

// ---- gemm1 fused: qkv = x_bf @ Wqkv^T + b; writes Q->qbuf, K/V->packed kvp -
__global__ __launch_bounds__(256) void gemm_qkv(
    const u16* __restrict__ A, const u16* __restrict__ BT,
    const float* __restrict__ bias, u16* __restrict__ qbuf,
    u16* __restrict__ kvp) {
    const int K = 1024;
    __shared__ __align__(16) u16 SMEM[24576];   // As[3][4096] | Bs[3][4096]
    int bm = blockIdx.x, bn = blockIdx.y;
    int t = threadIdx.x;
    int lane = t & 63, wave = t >> 6;
    int wr = wave >> 1, wc = wave & 1;
    f32x4 acc[4][4] = {};

    const u16* gA = A + (size_t)(bm * 128) * K;
    const u16* gB = BT + (size_t)(bn * 128) * K;

    auto stage = [&](int buf, int k0) {
#pragma unroll
        for (int i = 0; i < 2; i++) {
            int o = i * 4096 + t * 16;
            int row = o >> 6;
            int cb = (o & 63) ^ (((row >> 1) & 3) << 4);
            gload16(gA + (size_t)row * K + k0 + (cb >> 1),
                    &SMEM[buf * 4096 + i * 2048 + (t & 192) * 8]);
        }
#pragma unroll
        for (int i = 0; i < 2; i++) {
            int o = i * 4096 + t * 16;
            int row = o >> 6;
            int cb = (o & 63) ^ (((row >> 1) & 3) << 4);
            gload16(gB + (size_t)row * K + k0 + (cb >> 1),
                    &SMEM[12288 + buf * 4096 + i * 2048 + (t & 192) * 8]);
        }
    };

    stage(0, 0);
    stage(1, 32);
    WAITV(4);
    __builtin_amdgcn_sched_barrier(0);
    __builtin_amdgcn_s_barrier();
    __builtin_amdgcn_sched_barrier(0);

    for (int tt = 0; tt < 32; tt++) {
        bool pre = (tt + 2 < 32);
        if (pre) stage((tt + 2) % 3, (tt + 2) << 5);
        int row16 = lane & 15;
        int colb = ((lane >> 4) * 16) ^ (((row16 >> 1) & 3) << 4);
        const u16* Ab = &SMEM[(tt % 3) * 4096];
        const u16* Bb = &SMEM[12288 + (tt % 3) * 4096];
        short8 af[4], bf[4];
#pragma unroll
        for (int m = 0; m < 4; m++)
            af[m] = *(const short8*)&Ab[(wr * 64 + m * 16 + row16) * 32 + (colb >> 1)];
#pragma unroll
        for (int n = 0; n < 4; n++)
            bf[n] = *(const short8*)&Bb[(wc * 64 + n * 16 + row16) * 32 + (colb >> 1)];
        __builtin_amdgcn_s_setprio(1);
#pragma unroll
        for (int m = 0; m < 4; m++)
#pragma unroll
            for (int n = 0; n < 4; n++)
                acc[m][n] = __builtin_amdgcn_mfma_f32_16x16x32_bf16(
                    af[m], bf[n], acc[m][n], 0, 0, 0);
        __builtin_amdgcn_s_setprio(0);
        if (pre) { WAITV(4); } else { WAITV(0); }
        __builtin_amdgcn_sched_barrier(0);
        __builtin_amdgcn_s_barrier();
        __builtin_amdgcn_sched_barrier(0);
    }

    int l15 = lane & 15, hi = lane >> 4;
    if (bn < 8) {
        // ---- Q: straight rows into qbuf [4096][1024] ----
#pragma unroll
        for (int m = 0; m < 4; m++)
#pragma unroll
            for (int n = 0; n < 4; n++) {
                int col = bn * 128 + wc * 64 + n * 16 + l15;
                float bv = bias[col];
#pragma unroll
                for (int r = 0; r < 4; r++) {
                    int row = bm * 128 + wr * 64 + m * 16 + hi * 4 + r;
                    qbuf[(size_t)row * 1024 + col] = f2bf(acc[m][n][r] + bv);
                }
            }
    } else if (bn < 16) {
        // ---- K: packed kvp[bh][tt][0][k][d] ----
        int h2 = (bn - 8) * 2 + wc;     // head (wave-uniform)
#pragma unroll
        for (int m = 0; m < 4; m++)
#pragma unroll
            for (int n = 0; n < 4; n++) {
                int d = n * 16 + l15;
                float bv = bias[1024 + h2 * 64 + d];
#pragma unroll
                for (int r = 0; r < 4; r++) {
                    int row = bm * 128 + wr * 64 + m * 16 + hi * 4 + r;
                    int b = row >> 11;
                    int tt = (row & 2047) >> 6;
                    int k = row & 63;
                    kvp[(size_t)(b * 16 + h2) * 262144 + tt * 8192 + k * 64 + d] =
                        f2bf(acc[m][n][r] + bv);
                }
            }
    } else {
        // ---- V: transpose via per-wave LDS, packed kvp[bh][tt][1][d][k] ----
        int h2 = (bn - 16) * 2 + wc;
        int rowbase = bm * 128 + wr * 64;
        int b = rowbase >> 11;
        int tt = (rowbase & 2047) >> 6;
        u16* wl = &SMEM[wave * 4608];   // 64 x stride-72, post-barrier reuse
#pragma unroll
        for (int m = 0; m < 4; m++)
#pragma unroll
            for (int n = 0; n < 4; n++) {
                int d = n * 16 + l15;
                float bv = bias[2048 + h2 * 64 + d];
                unsigned p0 = cvtpk(acc[m][n][0] + bv, acc[m][n][1] + bv);
                unsigned p1 = cvtpk(acc[m][n][2] + bv, acc[m][n][3] + bv);
                *(uint2v*)&wl[d * 72 + m * 16 + hi * 4] = (uint2v){p0, p1};
            }
        u16* dst = kvp + (size_t)(b * 16 + h2) * 262144 + tt * 8192 + 4096;
#pragma unroll
        for (int i = 0; i < 8; i++)
            *(uint4v*)(dst + lane * 64 + i * 8) = *(const uint4v*)&wl[lane * 72 + i * 8];
    }
}

// ------- gemm2: attnb @ Wo^T + bo (BN=64, counted-vmcnt, swizzled) --------
__global__ __launch_bounds__(256) void gemm_out(
    const u16* __restrict__ A, const u16* __restrict__ BT,
    const float* __restrict__ bias, float* __restrict__ Cout) {
    const int K = 1024, N = 1024;
    __shared__ __align__(16) u16 As[3][4096];
    __shared__ __align__(16) u16 Bs[3][2048];
    int bm = blockIdx.x, bn = blockIdx.y;
    int t = threadIdx.x;
    int lane = t & 63, wave = t >> 6;
    int wr = wave >> 1, wc = wave & 1;
    f32x4 acc[4][2] = {};

    const u16* gA = A + (size_t)(bm * 128) * K;
    const u16* gB = BT + (size_t)(bn * 64) * K;

    auto stage = [&](int buf, int k0) {
#pragma unroll
        for (int i = 0; i < 2; i++) {
            int o = i * 4096 + t * 16;
            int row = o >> 6;
            int cb = (o & 63) ^ (((row >> 1) & 3) << 4);
            gload16(gA + (size_t)row * K + k0 + (cb >> 1),
                    &As[buf][i * 2048 + (t & 192) * 8]);
        }
        {
            int o = t * 16;
            int row = o >> 6;
            int cb = (o & 63) ^ (((row >> 1) & 3) << 4);
            gload16(gB + (size_t)row * K + k0 + (cb >> 1),
                    &Bs[buf][(t & 192) * 8]);
        }
    };

    stage(0, 0);
    stage(1, 32);
    WAITV(3);
    __builtin_amdgcn_sched_barrier(0);
    __builtin_amdgcn_s_barrier();
    __builtin_amdgcn_sched_barrier(0);

    for (int tt = 0; tt < 32; tt++) {
        bool pre = (tt + 2 < 32);
        if (pre) stage((tt + 2) % 3, (tt + 2) << 5);
        int row16 = lane & 15;
        int colb = ((lane >> 4) * 16) ^ (((row16 >> 1) & 3) << 4);
        short8 af[4], bf[2];
#pragma unroll
        for (int m = 0; m < 4; m++)
            af[m] = *(const short8*)&As[tt % 3][(wr * 64 + m * 16 + row16) * 32 + (colb >> 1)];
#pragma unroll
        for (int n = 0; n < 2; n++)
            bf[n] = *(const short8*)&Bs[tt % 3][(wc * 32 + n * 16 + row16) * 32 + (colb >> 1)];
        __builtin_amdgcn_s_setprio(1);
#pragma unroll
        for (int m = 0; m < 4; m++)
#pragma unroll
            for (int n = 0; n < 2; n++)
                acc[m][n] = __builtin_amdgcn_mfma_f32_16x16x32_bf16(
                    af[m], bf[n], acc[m][n], 0, 0, 0);
        __builtin_amdgcn_s_setprio(0);
        if (pre) { WAITV(3); } else { WAITV(0); }
        __builtin_amdgcn_sched_barrier(0);
        __builtin_amdgcn_s_barrier();
        __builtin_amdgcn_sched_barrier(0);
    }

#pragma unroll
    for (int m = 0; m < 4; m++)
#pragma unroll
        for (int n = 0; n < 2; n++) {
            int col = bn * 64 + wc * 32 + n * 16 + (lane & 15);
            float bv = bias[col];
#pragma unroll
            for (int r = 0; r < 4; r++) {
                int row = bm * 128 + wr * 64 + m * 16 + (lane >> 4) * 4 + r;
                Cout[(size_t)row * N + col] = acc[m][n][r] + bv;
            }
        }
}

// ------- causal flash attention v11: K-LDS triple, V direct, chunk-8 ------
// 1280 blocks (40 chunks x 32 bh). Every block runs 4-8 k-tiles (uniform).
// K tiles in 24KB LDS (counted vmcnt); V frags direct from packed kvp at
// iter start; swapped 32x32 MFMA, in-register P, static-offset softmax.
// Partials (nc>1) -> ws; attn_merge combines 2-4.
__global__ __launch_bounds__(256, 3) void attn_kernel(
    const u16* __restrict__ qbuf, const u16* __restrict__ kvp,
    u16* __restrict__ attn, float* __restrict__ part_o,
    float* __restrict__ part_l) {
    int bid = blockIdx.x;
    int bh = bid & 31;
    int j = bid >> 5;                    // 0..39
    int sp, c, nc;
    if (j < 4)       { sp = j;                c = 0;            nc = 1; }
    else if (j < 12) { int i = j - 4;  sp = 4 + (i >> 1); c = i & 1; nc = 2; }
    else if (j < 24) { int i = j - 12; sp = 8 + i / 3;    c = i % 3; nc = 3; }
    else             { int i = j - 24; sp = 12 + (i >> 2); c = i & 3; nc = 4; }
    int nt = 2 * sp + 2;
    int tbeg = c * nt / nc, tend = (c + 1) * nt / nc;

    int b = bh >> 4, h = bh & 15;
    int t = threadIdx.x;
    int lane = t & 63, w = t >> 6;
    int qb = sp * 128 + w * 32;
    int kend = qb + 32;
    int l31 = lane & 31, hi32 = lane >> 5;
    int swz = (lane & 7) << 4;

    __shared__ __align__(16) u16 Ks[3][4096];   // 24 KB

    const u16* kvb = kvp + (size_t)bh * 262144;

    auto stageK = [&](int buf, int tt) {
        const char* g0 = (const char*)(kvb + (size_t)tt * 8192);
#pragma unroll
        for (int i = 0; i < 2; i++) {
            int o = i * 4096 + t * 16;
            int row = o >> 7;
            int cb = (o & 127) ^ ((row & 7) << 4);
            gload16((const u16*)(g0 + row * 128 + cb),
                    &Ks[buf][i * 2048 + (t & 192) * 8]);
        }
    };

    short8 qf[4];
    {
        const u16* q0 = qbuf + (size_t)(b * 2048 + qb + l31) * 1024 + h * 64 + hi32 * 8;
#pragma unroll
        for (int dd = 0; dd < 4; dd++) qf[dd] = *(const short8*)(q0 + dd * 16);
    }
    stageK(tbeg % 3, tbeg);
    stageK((tbeg + 1) % 3, tbeg + 1);

    float l_lane = 0.f;
    f32x16 oT[2] = {};

    const float C1 = 0.1803368880f;    // 0.125/ln2
    const float C2 = -17.3123404907f;  // 12/ln2

    WAITV(2);
    __builtin_amdgcn_sched_barrier(0);
    __builtin_amdgcn_s_barrier();
    __builtin_amdgcn_sched_barrier(0);

    for (int tt = tbeg; tt < tend; tt++) {
        bool pre = (tt + 2 < tend);
        int k0 = tt * 64;
        bool active = (k0 < kend);
        short8 vf[2][4];
        if (active) {
            // V fragments direct from packed tile (issued early, used late)
            const u16* vp = kvb + (size_t)tt * 8192 + 4096;
#pragma unroll
            for (int mb = 0; mb < 2; mb++)
#pragma unroll
                for (int kk = 0; kk < 4; kk++)
                    vf[mb][kk] = *(const short8*)(vp + (mb * 32 + l31) * 64 + kk * 16 + hi32 * 8);
        }
        if (pre) stageK((tt + 2) % 3, tt + 2);
        if (active) {
            const u16* Ksb = Ks[tt % 3];
            f32x16 sc[2];
            __builtin_amdgcn_s_setprio(1);
#pragma unroll
            for (int kb = 0; kb < 2; kb++) {
                f32x16 z = {};
#pragma unroll
                for (int dd = 0; dd < 4; dd++) {
                    int off = (kb * 32 + l31) * 64 + (((dd * 32 + hi32 * 16) ^ swz) >> 1);
                    short8 kf = *(const short8*)&Ksb[off];
                    z = __builtin_amdgcn_mfma_f32_32x32x16_bf16(kf, qf[dd], z, 0, 0, 0);
                }
                sc[kb] = z;
            }
            __builtin_amdgcn_s_setprio(0);

            int q_g = qb + l31;
            if (k0 + 64 > qb) {
#pragma unroll
                for (int kb = 0; kb < 2; kb++)
#pragma unroll
                    for (int r = 0; r < 16; r++) {
                        int kg = k0 + kb * 32 + (r & 3) + 8 * (r >> 2) + 4 * hi32;
                        float v = (kg <= q_g) ? sc[kb][r] : -1e30f;
                        float pe = __builtin_amdgcn_exp2f(fmaf(v, C1, C2));
                        sc[kb][r] = pe;
                        l_lane += pe;
                    }
            } else {
#pragma unroll
                for (int kb = 0; kb < 2; kb++)
#pragma unroll
                    for (int r = 0; r < 16; r++) {
                        float pe = __builtin_amdgcn_exp2f(fmaf(sc[kb][r], C1, C2));
                        sc[kb][r] = pe;
                        l_lane += pe;
                    }
            }

            __builtin_amdgcn_s_setprio(1);
#pragma unroll
            for (int kb = 0; kb < 2; kb++)
#pragma unroll
                for (int cset = 0; cset < 2; cset++) {
                    int kk = kb * 2 + cset;
                    unsigned A0 = cvtpk(sc[kb][cset * 8 + 0], sc[kb][cset * 8 + 1]);
                    unsigned A1 = cvtpk(sc[kb][cset * 8 + 2], sc[kb][cset * 8 + 3]);
                    unsigned A2 = cvtpk(sc[kb][cset * 8 + 4], sc[kb][cset * 8 + 5]);
                    unsigned A3 = cvtpk(sc[kb][cset * 8 + 6], sc[kb][cset * 8 + 7]);
                    unsigned za = hi32 ? A0 : A2;
                    unsigned zb = hi32 ? A1 : A3;
                    unsigned sa = (unsigned)__shfl_xor((int)za, 32, 64);
                    unsigned sb = (unsigned)__shfl_xor((int)zb, 32, 64);
                    uint4v wv;
                    wv[0] = hi32 ? sa : A0;
                    wv[1] = hi32 ? sb : A1;
                    wv[2] = hi32 ? A2 : sa;
                    wv[3] = hi32 ? A3 : sb;
                    short8 pb = __builtin_bit_cast(short8, wv);
                    oT[0] = __builtin_amdgcn_mfma_f32_32x32x16_bf16(vf[0][kk], pb, oT[0], 0, 0, 0);
                    oT[1] = __builtin_amdgcn_mfma_f32_32x32x16_bf16(vf[1][kk], pb, oT[1], 0, 0, 0);
                }
            __builtin_amdgcn_s_setprio(0);
        }
        if (pre) { WAITV(2); } else { WAITV(0); }
        __builtin_amdgcn_sched_barrier(0);
        __builtin_amdgcn_s_barrier();
        __builtin_amdgcn_sched_barrier(0);
    }

    if (nc > 1) {
        // partial: slot = bh*36 + off(sp,c)
        int off = (sp < 8) ? (sp - 4) * 2 + c
                 : (sp < 12) ? 8 + (sp - 8) * 3 + c
                             : 20 + (sp - 12) * 4 + c;
        int slot = bh * 36 + off;
        float* po = part_o + (size_t)slot * 8192;
        int ql = w * 32 + l31;
        float lf = l_lane + __shfl_xor(l_lane, 32, 64);
        if (hi32 == 0) part_l[slot * 128 + ql] = lf;
#pragma unroll
        for (int mb = 0; mb < 2; mb++)
#pragma unroll
            for (int g = 0; g < 4; g++) {
                int d0 = mb * 32 + g * 8 + hi32 * 4;
                f32x4 v = {oT[mb][4 * g], oT[mb][4 * g + 1],
                           oT[mb][4 * g + 2], oT[mb][4 * g + 3]};
                *(f32x4*)(po + ql * 64 + d0) = v;
            }
        return;
    }

    float lf = l_lane + __shfl_xor(l_lane, 32, 64);
    float linv = __builtin_amdgcn_rcpf(lf);
    u16* gp = attn + (size_t)(b * 2048 + qb + l31) * 1024 + h * 64;
#pragma unroll
    for (int mb = 0; mb < 2; mb++)
#pragma unroll
        for (int g = 0; g < 4; g++) {
            unsigned w0 = cvtpk(oT[mb][4 * g] * linv, oT[mb][4 * g + 1] * linv);
            unsigned w1 = cvtpk(oT[mb][4 * g + 2] * linv, oT[mb][4 * g + 3] * linv);
            int d0 = mb * 32 + g * 8 + hi32 * 4;
            *(uint2v*)(gp + d0) = (uint2v){w0, w1};
        }
}

// ---- merge 2-4 split-K partials: out = sum(o_i)/sum(l_i), bf16 ----
__global__ __launch_bounds__(256) void attn_merge(
    const float* __restrict__ part_o, const float* __restrict__ part_l,
    u16* __restrict__ attn) {
    int bid = blockIdx.x;
    int bh = bid & 31;
    int spi = bid >> 5;                  // 0..11
    int sp = spi + 4;
    int nc = (spi < 4) ? 2 : (spi < 8) ? 3 : 4;
    int off = (spi < 4) ? spi * 2 : (spi < 8) ? 8 + (spi - 4) * 3
                                              : 20 + (spi - 8) * 4;
    int slot0 = bh * 36 + off;
    int b = bh >> 4, h = bh & 15;
    int t = threadIdx.x;
    int r = t >> 1;
    int d0 = (t & 1) * 32;
    float l = 0.f;
    for (int i = 0; i < nc; i++) l += part_l[(slot0 + i) * 128 + r];
    float linv = __builtin_amdgcn_rcpf(l);
#pragma unroll
    for (int g = 0; g < 4; g++) {
        float4v s0 = {0.f, 0.f, 0.f, 0.f}, s1 = {0.f, 0.f, 0.f, 0.f};
        for (int i = 0; i < nc; i++) {
            const float* p = part_o + (size_t)(slot0 + i) * 8192 + r * 64 + d0 + g * 8;
            s0 += *(const float4v*)p;
            s1 += *(const float4v*)(p + 4);
        }
        uint4v wv;
        wv[0] = cvtpk(s0[0] * linv, s0[1] * linv);
        wv[1] = cvtpk(s0[2] * linv, s0[3] * linv);
        wv[2] = cvtpk(s1[0] * linv, s1[1] * linv);
        wv[3] = cvtpk(s1[2] * linv, s1[3] * linv);
        u16* gp = attn + (size_t)(b * 2048 + sp * 128 + r) * 1024 + h * 64 + d0 + g * 8;
        *(uint4v*)gp = wv;
    }
}

extern "C" void kernel_launch(void* const* d_in, const int* in_sizes, int n_in,
                              void* d_out, int out_size, void* d_ws, size_t ws_size,
                              hipStream_t stream) {
    const float* x    = (const float*)d_in[0];
    const float* Wqkv = (const float*)d_in[1];
    const float* bqkv = (const float*)d_in[2];
    const float* Wo   = (const float*)d_in[3];
    const float* bo   = (const float*)d_in[4];
    float* out = (float*)d_out;

    char* ws = (char*)d_ws;
    u16* x_bf   = (u16*)(ws);                     //  8 MB (attnb reuses after)
    u16* attnb  = (u16*)(ws);                     //  8 MB
    u16* wqkvT  = (u16*)(ws + (8ull << 20));      //  6 MB
    u16* woT    = (u16*)(ws + (14ull << 20));     //  2 MB
    u16* qbuf   = (u16*)(ws + (16ull << 20));     //  8 MB: [4096][1024]
    u16* kvp    = (u16*)(ws + (24ull << 20));     // 16 MB: [32][32][2][64][64]
    float* part_o = (float*)(ws + (40ull << 20)); // 36 MB: [1152][8192]
    float* part_l = (float*)(ws + (76ull << 20)); // 0.6 MB

    prep<<<3072, 256, 0, stream>>>(x, Wqkv, Wo, x_bf, wqkvT, woT);
    gemm_qkv<<<dim3(32, 24), 256, 0, stream>>>(x_bf, wqkvT, bqkv, qbuf, kvp);
    attn_kernel<<<1280, 256, 0, stream>>>(qbuf, kvp, attnb, part_o, part_l);
    attn_merge<<<384, 256, 0, stream>>>(part_o, part_l, attnb);
    gemm_out<<<dim3(32, 16), 256, 0, stream>>>(attnb, woT, bo, out);
}

// Round 12
// 109.315 us; speedup vs baseline: 1.2530x; 1.2530x over previous
//
#include <hip/hip_runtime.h>
#include <hip/hip_bf16.h>

typedef unsigned short u16;
typedef __attribute__((ext_vector_type(8))) short short8;
typedef __attribute__((ext_vector_type(4))) float f32x4;
typedef __attribute__((ext_vector_type(16))) float f32x16;
typedef __attribute__((ext_vector_type(4))) float float4v;
typedef __attribute__((ext_vector_type(4))) unsigned int uint4v;
typedef __attribute__((ext_vector_type(2))) unsigned int uint2v;

__device__ __forceinline__ u16 f2bf(float f) {
    union { float f; unsigned u; } x;
    x.f = f;
    unsigned r = x.u + 0x7fffu + ((x.u >> 16) & 1u);  // RNE
    return (u16)(r >> 16);
}

__device__ __forceinline__ unsigned cvtpk(float lo, float hi) {
    unsigned r;
    asm("v_cvt_pk_bf16_f32 %0, %1, %2" : "=v"(r) : "v"(lo), "v"(hi));
    return r;
}

__device__ __forceinline__ void gload16(const u16* g, u16* l) {
    __builtin_amdgcn_global_load_lds(
        (const __attribute__((address_space(1))) unsigned*)g,
        (__attribute__((address_space(3))) unsigned*)l, 16, 0, 0);
}

#define WAITV(n) asm volatile("s_waitcnt vmcnt(" #n ")" ::: "memory")

// ---------------- fused prep: cast x + transpose Wqkv + transpose Wo -------
__global__ __launch_bounds__(256) void prep(
    const float* __restrict__ x, const float* __restrict__ Wqkv,
    const float* __restrict__ Wo, u16* __restrict__ x_bf,
    u16* __restrict__ wqkvT, u16* __restrict__ woT) {
    int bid = blockIdx.x;
    int t = threadIdx.x;
    if (bid < 2048) {
        int i = bid * 256 + t;
        const float4v* s = (const float4v*)(x + (size_t)i * 8);
        float4v a = s[0], b = s[1];
        uint4v o;
        o[0] = (unsigned)f2bf(a[0]) | ((unsigned)f2bf(a[1]) << 16);
        o[1] = (unsigned)f2bf(a[2]) | ((unsigned)f2bf(a[3]) << 16);
        o[2] = (unsigned)f2bf(b[0]) | ((unsigned)f2bf(b[1]) << 16);
        o[3] = (unsigned)f2bf(b[2]) | ((unsigned)f2bf(b[3]) << 16);
        *(uint4v*)(x_bf + (size_t)i * 8) = o;
        return;
    }
    const float* src;
    u16* dst;
    int C, tid;
    if (bid < 2816) { tid = bid - 2048; src = Wqkv; dst = wqkvT; C = 3072; }
    else            { tid = bid - 2816; src = Wo;   dst = woT;   C = 1024; }
    int tr = (tid & 15) * 64;
    int tc = (tid >> 4) * 64;
    __shared__ __align__(16) u16 tile[64][72];
    int r = t >> 2;
    int c4 = (t & 3) * 16;
    const float4v* sp = (const float4v*)(src + (size_t)(tr + r) * C + tc + c4);
#pragma unroll
    for (int v = 0; v < 4; v++) {
        float4v xv = sp[v];
#pragma unroll
        for (int j = 0; j < 4; j++) tile[r][c4 + v * 4 + j] = f2bf(xv[j]);
    }
    __syncthreads();
    u16* dp = dst + (size_t)(tc + r) * 1024 + tr + c4;
#pragma unroll
    for (int i = 0; i < 16; i++) dp[i] = tile[c4 + i][r];
}

// ---- gemm1 fused: qkv = x_bf @ Wqkv^T + b; writes Q->qbuf, K/V->packed kvp -
__global__ __launch_bounds__(256) void gemm_qkv(
    const u16* __restrict__ A, const u16* __restrict__ BT,
    const float* __restrict__ bias, u16* __restrict__ qbuf,
    u16* __restrict__ kvp) {
    const int K = 1024;
    __shared__ __align__(16) u16 SMEM[24576];   // As[3][4096] | Bs[3][4096]
    int bm = blockIdx.x, bn = blockIdx.y;
    int t = threadIdx.x;
    int lane = t & 63, wave = t >> 6;
    int wr = wave >> 1, wc = wave & 1;
    f32x4 acc[4][4] = {};

    const u16* gA = A + (size_t)(bm * 128) * K;
    const u16* gB = BT + (size_t)(bn * 128) * K;

    auto stage = [&](int buf, int k0) {
#pragma unroll
        for (int i = 0; i < 2; i++) {
            int o = i * 4096 + t * 16;
            int row = o >> 6;
            int cb = (o & 63) ^ (((row >> 1) & 3) << 4);
            gload16(gA + (size_t)row * K + k0 + (cb >> 1),
                    &SMEM[buf * 4096 + i * 2048 + (t & 192) * 8]);
        }
#pragma unroll
        for (int i = 0; i < 2; i++) {
            int o = i * 4096 + t * 16;
            int row = o >> 6;
            int cb = (o & 63) ^ (((row >> 1) & 3) << 4);
            gload16(gB + (size_t)row * K + k0 + (cb >> 1),
                    &SMEM[12288 + buf * 4096 + i * 2048 + (t & 192) * 8]);
        }
    };

    stage(0, 0);
    stage(1, 32);
    WAITV(4);
    __builtin_amdgcn_sched_barrier(0);
    __builtin_amdgcn_s_barrier();
    __builtin_amdgcn_sched_barrier(0);

    for (int tt = 0; tt < 32; tt++) {
        bool pre = (tt + 2 < 32);
        if (pre) stage((tt + 2) % 3, (tt + 2) << 5);
        int row16 = lane & 15;
        int colb = ((lane >> 4) * 16) ^ (((row16 >> 1) & 3) << 4);
        const u16* Ab = &SMEM[(tt % 3) * 4096];
        const u16* Bb = &SMEM[12288 + (tt % 3) * 4096];
        short8 af[4], bf[4];
#pragma unroll
        for (int m = 0; m < 4; m++)
            af[m] = *(const short8*)&Ab[(wr * 64 + m * 16 + row16) * 32 + (colb >> 1)];
#pragma unroll
        for (int n = 0; n < 4; n++)
            bf[n] = *(const short8*)&Bb[(wc * 64 + n * 16 + row16) * 32 + (colb >> 1)];
        __builtin_amdgcn_s_setprio(1);
#pragma unroll
        for (int m = 0; m < 4; m++)
#pragma unroll
            for (int n = 0; n < 4; n++)
                acc[m][n] = __builtin_amdgcn_mfma_f32_16x16x32_bf16(
                    af[m], bf[n], acc[m][n], 0, 0, 0);
        __builtin_amdgcn_s_setprio(0);
        if (pre) { WAITV(4); } else { WAITV(0); }
        __builtin_amdgcn_sched_barrier(0);
        __builtin_amdgcn_s_barrier();
        __builtin_amdgcn_sched_barrier(0);
    }

    int l15 = lane & 15, hi = lane >> 4;
    if (bn < 8) {
        // ---- Q: straight rows into qbuf [4096][1024] ----
#pragma unroll
        for (int m = 0; m < 4; m++)
#pragma unroll
            for (int n = 0; n < 4; n++) {
                int col = bn * 128 + wc * 64 + n * 16 + l15;
                float bv = bias[col];
#pragma unroll
                for (int r = 0; r < 4; r++) {
                    int row = bm * 128 + wr * 64 + m * 16 + hi * 4 + r;
                    qbuf[(size_t)row * 1024 + col] = f2bf(acc[m][n][r] + bv);
                }
            }
    } else if (bn < 16) {
        // ---- K: packed kvp[bh][tt][0][k][d] ----
        int h2 = (bn - 8) * 2 + wc;     // head (wave-uniform)
#pragma unroll
        for (int m = 0; m < 4; m++)
#pragma unroll
            for (int n = 0; n < 4; n++) {
                int d = n * 16 + l15;
                float bv = bias[1024 + h2 * 64 + d];
#pragma unroll
                for (int r = 0; r < 4; r++) {
                    int row = bm * 128 + wr * 64 + m * 16 + hi * 4 + r;
                    int b = row >> 11;
                    int tt = (row & 2047) >> 6;
                    int k = row & 63;
                    kvp[(size_t)(b * 16 + h2) * 262144 + tt * 8192 + k * 64 + d] =
                        f2bf(acc[m][n][r] + bv);
                }
            }
    } else {
        // ---- V: transpose via per-wave LDS, packed kvp[bh][tt][1][d][k] ----
        int h2 = (bn - 16) * 2 + wc;
        int rowbase = bm * 128 + wr * 64;
        int b = rowbase >> 11;
        int tt = (rowbase & 2047) >> 6;
        u16* wl = &SMEM[wave * 4608];   // 64 x stride-72, post-barrier reuse
#pragma unroll
        for (int m = 0; m < 4; m++)
#pragma unroll
            for (int n = 0; n < 4; n++) {
                int d = n * 16 + l15;
                float bv = bias[2048 + h2 * 64 + d];
                unsigned p0 = cvtpk(acc[m][n][0] + bv, acc[m][n][1] + bv);
                unsigned p1 = cvtpk(acc[m][n][2] + bv, acc[m][n][3] + bv);
                *(uint2v*)&wl[d * 72 + m * 16 + hi * 4] = (uint2v){p0, p1};
            }
        u16* dst = kvp + (size_t)(b * 16 + h2) * 262144 + tt * 8192 + 4096;
#pragma unroll
        for (int i = 0; i < 8; i++)
            *(uint4v*)(dst + lane * 64 + i * 8) = *(const uint4v*)&wl[lane * 72 + i * 8];
    }
}

// ------- gemm2: attnb @ Wo^T + bo (BN=64, counted-vmcnt, swizzled) --------
__global__ __launch_bounds__(256) void gemm_out(
    const u16* __restrict__ A, const u16* __restrict__ BT,
    const float* __restrict__ bias, float* __restrict__ Cout) {
    const int K = 1024, N = 1024;
    __shared__ __align__(16) u16 As[3][4096];
    __shared__ __align__(16) u16 Bs[3][2048];
    int bm = blockIdx.x, bn = blockIdx.y;
    int t = threadIdx.x;
    int lane = t & 63, wave = t >> 6;
    int wr = wave >> 1, wc = wave & 1;
    f32x4 acc[4][2] = {};

    const u16* gA = A + (size_t)(bm * 128) * K;
    const u16* gB = BT + (size_t)(bn * 64) * K;

    auto stage = [&](int buf, int k0) {
#pragma unroll
        for (int i = 0; i < 2; i++) {
            int o = i * 4096 + t * 16;
            int row = o >> 6;
            int cb = (o & 63) ^ (((row >> 1) & 3) << 4);
            gload16(gA + (size_t)row * K + k0 + (cb >> 1),
                    &As[buf][i * 2048 + (t & 192) * 8]);
        }
        {
            int o = t * 16;
            int row = o >> 6;
            int cb = (o & 63) ^ (((row >> 1) & 3) << 4);
            gload16(gB + (size_t)row * K + k0 + (cb >> 1),
                    &Bs[buf][(t & 192) * 8]);
        }
    };

    stage(0, 0);
    stage(1, 32);
    WAITV(3);
    __builtin_amdgcn_sched_barrier(0);
    __builtin_amdgcn_s_barrier();
    __builtin_amdgcn_sched_barrier(0);

    for (int tt = 0; tt < 32; tt++) {
        bool pre = (tt + 2 < 32);
        if (pre) stage((tt + 2) % 3, (tt + 2) << 5);
        int row16 = lane & 15;
        int colb = ((lane >> 4) * 16) ^ (((row16 >> 1) & 3) << 4);
        short8 af[4], bf[2];
#pragma unroll
        for (int m = 0; m < 4; m++)
            af[m] = *(const short8*)&As[tt % 3][(wr * 64 + m * 16 + row16) * 32 + (colb >> 1)];
#pragma unroll
        for (int n = 0; n < 2; n++)
            bf[n] = *(const short8*)&Bs[tt % 3][(wc * 32 + n * 16 + row16) * 32 + (colb >> 1)];
        __builtin_amdgcn_s_setprio(1);
#pragma unroll
        for (int m = 0; m < 4; m++)
#pragma unroll
            for (int n = 0; n < 2; n++)
                acc[m][n] = __builtin_amdgcn_mfma_f32_16x16x32_bf16(
                    af[m], bf[n], acc[m][n], 0, 0, 0);
        __builtin_amdgcn_s_setprio(0);
        if (pre) { WAITV(3); } else { WAITV(0); }
        __builtin_amdgcn_sched_barrier(0);
        __builtin_amdgcn_s_barrier();
        __builtin_amdgcn_sched_barrier(0);
    }

#pragma unroll
    for (int m = 0; m < 4; m++)
#pragma unroll
        for (int n = 0; n < 2; n++) {
            int col = bn * 64 + wc * 32 + n * 16 + (lane & 15);
            float bv = bias[col];
#pragma unroll
            for (int r = 0; r < 4; r++) {
                int row = bm * 128 + wr * 64 + m * 16 + (lane >> 4) * 4 + r;
                Cout[(size_t)row * N + col] = acc[m][n][r] + bv;
            }
        }
}

// ------- causal flash attention v12 = R10 core + qbuf input ---------------
// 768 blocks (3/CU), (256,2) -> VGPR ~72. K+V tiles in 48KB triple-buffered
// LDS (counted vmcnt); heavy stripes (sp>=8) split in 2 k-halves -> partials.
__global__ __launch_bounds__(256, 2) void attn_kernel(
    const u16* __restrict__ qbuf, const u16* __restrict__ kvp,
    u16* __restrict__ attn, float* __restrict__ part_o,
    float* __restrict__ part_l) {
    int bid = blockIdx.x;
    int bh = bid & 31;
    int j = 23 - (bid >> 5);             // heavy (j>=8) first
    int sp, tbeg, tend, kc = 0;
    bool partial;
    if (j >= 8) {
        int idx = j - 8;                 // 0..15
        sp = 8 + (idx >> 1);
        kc = idx & 1;
        int half = sp + 1;
        partial = true;
        tbeg = kc ? half : 0;
        tend = kc ? 2 * sp + 2 : half;
    } else {
        sp = j;
        partial = false;
        tbeg = 0;
        tend = 2 * sp + 2;
    }
    int b = bh >> 4, h = bh & 15;
    int t = threadIdx.x;
    int lane = t & 63, w = t >> 6;
    int qb = sp * 128 + w * 32;
    int kend = qb + 32;
    int l31 = lane & 31, hi32 = lane >> 5;
    int swz = (lane & 7) << 4;

    __shared__ __align__(16) u16 KVb[24576];   // [3 bufs][K 4096 | V 4096]

    const u16* kvb = kvp + (size_t)bh * 262144;

    auto stage = [&](int buf, int tt) {
        const char* g0 = (const char*)(kvb + (size_t)tt * 8192);
#pragma unroll
        for (int kv2 = 0; kv2 < 2; kv2++)
#pragma unroll
            for (int i = 0; i < 2; i++) {
                int o = i * 4096 + t * 16;
                int row = o >> 7;
                int cb = (o & 127) ^ ((row & 7) << 4);
                gload16((const u16*)(g0 + kv2 * 8192 + row * 128 + cb),
                        &KVb[buf * 8192 + kv2 * 4096 + i * 2048 + (t & 192) * 8]);
            }
    };

    short8 qf[4];
    {
        const u16* q0 = qbuf + (size_t)(b * 2048 + qb + l31) * 1024 + h * 64 + hi32 * 8;
#pragma unroll
        for (int dd = 0; dd < 4; dd++) qf[dd] = *(const short8*)(q0 + dd * 16);
    }
    stage(tbeg % 3, tbeg);
    stage((tbeg + 1) % 3, tbeg + 1);

    float l_lane = 0.f;
    f32x16 oT[2] = {};

    const float C1 = 0.1803368880f;    // 0.125/ln2
    const float C2 = -17.3123404907f;  // 12/ln2

    WAITV(4);
    __builtin_amdgcn_sched_barrier(0);
    __builtin_amdgcn_s_barrier();
    __builtin_amdgcn_sched_barrier(0);

    for (int tt = tbeg; tt < tend; tt++) {
        bool pre = (tt + 2 < tend);
        if (pre) stage((tt + 2) % 3, tt + 2);
        int k0 = tt * 64;
        if (k0 < kend) {
            const u16* Ks = &KVb[(tt % 3) * 8192];
            const u16* Vs = Ks + 4096;
            f32x16 sc[2];
            __builtin_amdgcn_s_setprio(1);
#pragma unroll
            for (int kb = 0; kb < 2; kb++) {
                f32x16 z = {};
#pragma unroll
                for (int dd = 0; dd < 4; dd++) {
                    int off = (kb * 32 + l31) * 64 + (((dd * 32 + hi32 * 16) ^ swz) >> 1);
                    short8 kf = *(const short8*)&Ks[off];
                    z = __builtin_amdgcn_mfma_f32_32x32x16_bf16(kf, qf[dd], z, 0, 0, 0);
                }
                sc[kb] = z;
            }
            __builtin_amdgcn_s_setprio(0);

            float p[2][16];
            int q_g = qb + l31;
            if (k0 + 64 > qb) {
#pragma unroll
                for (int kb = 0; kb < 2; kb++)
#pragma unroll
                    for (int r = 0; r < 16; r++) {
                        int kg = k0 + kb * 32 + (r & 3) + 8 * (r >> 2) + 4 * hi32;
                        float v = (kg <= q_g) ? sc[kb][r] : -1e30f;
                        float pe = __builtin_amdgcn_exp2f(fmaf(v, C1, C2));
                        p[kb][r] = pe;
                        l_lane += pe;
                    }
            } else {
#pragma unroll
                for (int kb = 0; kb < 2; kb++)
#pragma unroll
                    for (int r = 0; r < 16; r++) {
                        float pe = __builtin_amdgcn_exp2f(fmaf(sc[kb][r], C1, C2));
                        p[kb][r] = pe;
                        l_lane += pe;
                    }
            }

            short8 pb[4];
#pragma unroll
            for (int kb = 0; kb < 2; kb++)
#pragma unroll
                for (int cset = 0; cset < 2; cset++) {
                    const float* pp = &p[kb][cset * 8];
                    unsigned A0 = cvtpk(pp[0], pp[1]);
                    unsigned A1 = cvtpk(pp[2], pp[3]);
                    unsigned A2 = cvtpk(pp[4], pp[5]);
                    unsigned A3 = cvtpk(pp[6], pp[7]);
                    unsigned za = hi32 ? A0 : A2;
                    unsigned zb = hi32 ? A1 : A3;
                    unsigned sa = (unsigned)__shfl_xor((int)za, 32, 64);
                    unsigned sb = (unsigned)__shfl_xor((int)zb, 32, 64);
                    uint4v wv;
                    wv[0] = hi32 ? sa : A0;
                    wv[1] = hi32 ? sb : A1;
                    wv[2] = hi32 ? A2 : sa;
                    wv[3] = hi32 ? A3 : sb;
                    pb[kb * 2 + cset] = __builtin_bit_cast(short8, wv);
                }

            __builtin_amdgcn_s_setprio(1);
#pragma unroll
            for (int mb = 0; mb < 2; mb++)
#pragma unroll
                for (int kk = 0; kk < 4; kk++) {
                    int off = (mb * 32 + l31) * 64 + (((kk * 32 + hi32 * 16) ^ swz) >> 1);
                    short8 vf = *(const short8*)&Vs[off];
                    oT[mb] = __builtin_amdgcn_mfma_f32_32x32x16_bf16(vf, pb[kk], oT[mb], 0, 0, 0);
                }
            __builtin_amdgcn_s_setprio(0);
        }
        if (pre) { WAITV(4); } else { WAITV(0); }
        __builtin_amdgcn_sched_barrier(0);
        __builtin_amdgcn_s_barrier();
        __builtin_amdgcn_sched_barrier(0);
    }

    if (partial) {
        int blk = (bh * 8 + (sp - 8)) * 2 + kc;
        float* po = part_o + (size_t)blk * 8192;
        int lr = w * 32 + l31;
        float lf = l_lane + __shfl_xor(l_lane, 32, 64);
        if (hi32 == 0) part_l[blk * 128 + lr] = lf;
#pragma unroll
        for (int mb = 0; mb < 2; mb++)
#pragma unroll
            for (int r = 0; r < 16; r++) {
                int d = mb * 32 + (r & 3) + 8 * (r >> 2) + 4 * hi32;
                po[lr * 64 + d] = oT[mb][r];
            }
        return;
    }

    float lf = l_lane + __shfl_xor(l_lane, 32, 64);
    float linv = __builtin_amdgcn_rcpf(lf);
    u16* gp = attn + (size_t)(b * 2048 + qb + l31) * 1024 + h * 64;
#pragma unroll
    for (int mb = 0; mb < 2; mb++)
#pragma unroll
        for (int g = 0; g < 4; g++) {
            unsigned w0 = cvtpk(oT[mb][4 * g] * linv, oT[mb][4 * g + 1] * linv);
            unsigned w1 = cvtpk(oT[mb][4 * g + 2] * linv, oT[mb][4 * g + 3] * linv);
            int d0 = mb * 32 + g * 8 + hi32 * 4;
            *(uint2v*)(gp + d0) = (uint2v){w0, w1};
        }
}

// ---- merge split-K partials: out = (o0+o1)/(l0+l1), bf16 ----
__global__ __launch_bounds__(256) void attn_merge(
    const float* __restrict__ part_o, const float* __restrict__ part_l,
    u16* __restrict__ attn) {
    int bid = blockIdx.x;
    int bh = bid & 31;
    int sp8 = bid >> 5;                  // 0..7
    int sp = sp8 + 8;
    int b = bh >> 4, h = bh & 15;
    int t = threadIdx.x;
    int blk0 = (bh * 8 + sp8) * 2;
    const float* o0 = part_o + (size_t)blk0 * 8192;
    const float* o1 = o0 + 8192;
    const float* l0 = part_l + blk0 * 128;
    const float* l1 = l0 + 128;
#pragma unroll
    for (int i = 0; i < 4; i++) {
        int r = (t >> 3) + i * 32;
        int d0 = (t & 7) * 8;
        float linv = __builtin_amdgcn_rcpf(l0[r] + l1[r]);
        const float* a = o0 + r * 64 + d0;
        const float* c = o1 + r * 64 + d0;
        uint4v w;
#pragma unroll
        for (int k = 0; k < 4; k++)
            w[k] = cvtpk((a[2 * k] + c[2 * k]) * linv,
                         (a[2 * k + 1] + c[2 * k + 1]) * linv);
        u16* gp = attn + (size_t)(b * 2048 + sp * 128 + r) * 1024 + h * 64 + d0;
        *(uint4v*)gp = w;
    }
}

extern "C" void kernel_launch(void* const* d_in, const int* in_sizes, int n_in,
                              void* d_out, int out_size, void* d_ws, size_t ws_size,
                              hipStream_t stream) {
    const float* x    = (const float*)d_in[0];
    const float* Wqkv = (const float*)d_in[1];
    const float* bqkv = (const float*)d_in[2];
    const float* Wo   = (const float*)d_in[3];
    const float* bo   = (const float*)d_in[4];
    float* out = (float*)d_out;

    char* ws = (char*)d_ws;
    u16* x_bf   = (u16*)(ws);                     //  8 MB (attnb reuses after)
    u16* attnb  = (u16*)(ws);                     //  8 MB
    u16* wqkvT  = (u16*)(ws + (8ull << 20));      //  6 MB
    u16* woT    = (u16*)(ws + (14ull << 20));     //  2 MB
    u16* qbuf   = (u16*)(ws + (16ull << 20));     //  8 MB: [4096][1024]
    u16* kvp    = (u16*)(ws + (24ull << 20));     // 16 MB: [32][32][2][64][64]
    float* part_o = (float*)(ws + (40ull << 20)); // 16 MB: [512][8192]
    float* part_l = (float*)(ws + (56ull << 20)); // 256 KB

    prep<<<3072, 256, 0, stream>>>(x, Wqkv, Wo, x_bf, wqkvT, woT);
    gemm_qkv<<<dim3(32, 24), 256, 0, stream>>>(x_bf, wqkvT, bqkv, qbuf, kvp);
    attn_kernel<<<768, 256, 0, stream>>>(qbuf, kvp, attnb, part_o, part_l);
    attn_merge<<<256, 256, 0, stream>>>(part_o, part_l, attnb);
    gemm_out<<<dim3(32, 16), 256, 0, stream>>>(attnb, woT, bo, out);
}

// Round 13
// 109.170 us; speedup vs baseline: 1.2546x; 1.0013x over previous
//
#include <hip/hip_runtime.h>
#include <hip/hip_bf16.h>

typedef unsigned short u16;
typedef __attribute__((ext_vector_type(8))) short short8;
typedef __attribute__((ext_vector_type(4))) float f32x4;
typedef __attribute__((ext_vector_type(16))) float f32x16;
typedef __attribute__((ext_vector_type(4))) float float4v;
typedef __attribute__((ext_vector_type(4))) unsigned int uint4v;
typedef __attribute__((ext_vector_type(2))) unsigned int uint2v;

__device__ __forceinline__ u16 f2bf(float f) {
    union { float f; unsigned u; } x;
    x.f = f;
    unsigned r = x.u + 0x7fffu + ((x.u >> 16) & 1u);  // RNE
    return (u16)(r >> 16);
}

__device__ __forceinline__ unsigned cvtpk(float lo, float hi) {
    unsigned r;
    asm("v_cvt_pk_bf16_f32 %0, %1, %2" : "=v"(r) : "v"(lo), "v"(hi));
    return r;
}

__device__ __forceinline__ void gload16(const u16* g, u16* l) {
    __builtin_amdgcn_global_load_lds(
        (const __attribute__((address_space(1))) unsigned*)g,
        (__attribute__((address_space(3))) unsigned*)l, 16, 0, 0);
}

// NOTE (R13): counted vmcnt + raw barrier, NO sched_barrier(0) fences.
// m141: sched_barrier(0) order-pinning costs 874->510 TF on this exact
// structure (defeats compiler cross-iteration pipelining). The fences are
// only needed for inline-asm ds_reads (rule #18), which we don't use.
#define WAITV(n) asm volatile("s_waitcnt vmcnt(" #n ")" ::: "memory")

// ---------------- fused prep: cast x + transpose Wqkv + transpose Wo -------
__global__ __launch_bounds__(256) void prep(
    const float* __restrict__ x, const float* __restrict__ Wqkv,
    const float* __restrict__ Wo, u16* __restrict__ x_bf,
    u16* __restrict__ wqkvT, u16* __restrict__ woT) {
    int bid = blockIdx.x;
    int t = threadIdx.x;
    if (bid < 2048) {
        int i = bid * 256 + t;
        const float4v* s = (const float4v*)(x + (size_t)i * 8);
        float4v a = s[0], b = s[1];
        uint4v o;
        o[0] = (unsigned)f2bf(a[0]) | ((unsigned)f2bf(a[1]) << 16);
        o[1] = (unsigned)f2bf(a[2]) | ((unsigned)f2bf(a[3]) << 16);
        o[2] = (unsigned)f2bf(b[0]) | ((unsigned)f2bf(b[1]) << 16);
        o[3] = (unsigned)f2bf(b[2]) | ((unsigned)f2bf(b[3]) << 16);
        *(uint4v*)(x_bf + (size_t)i * 8) = o;
        return;
    }
    const float* src;
    u16* dst;
    int C, tid;
    if (bid < 2816) { tid = bid - 2048; src = Wqkv; dst = wqkvT; C = 3072; }
    else            { tid = bid - 2816; src = Wo;   dst = woT;   C = 1024; }
    int tr = (tid & 15) * 64;
    int tc = (tid >> 4) * 64;
    __shared__ __align__(16) u16 tile[64][72];
    int r = t >> 2;
    int c4 = (t & 3) * 16;
    const float4v* sp = (const float4v*)(src + (size_t)(tr + r) * C + tc + c4);
#pragma unroll
    for (int v = 0; v < 4; v++) {
        float4v xv = sp[v];
#pragma unroll
        for (int j = 0; j < 4; j++) tile[r][c4 + v * 4 + j] = f2bf(xv[j]);
    }
    __syncthreads();
    u16* dp = dst + (size_t)(tc + r) * 1024 + tr + c4;
#pragma unroll
    for (int i = 0; i < 16; i++) dp[i] = tile[c4 + i][r];
}

// ---- gemm1 fused: qkv = x_bf @ Wqkv^T + b; writes Q->qbuf, K/V->packed kvp -
__global__ __launch_bounds__(256) void gemm_qkv(
    const u16* __restrict__ A, const u16* __restrict__ BT,
    const float* __restrict__ bias, u16* __restrict__ qbuf,
    u16* __restrict__ kvp) {
    const int K = 1024;
    __shared__ __align__(16) u16 SMEM[24576];   // As[3][4096] | Bs[3][4096]
    int bm = blockIdx.x, bn = blockIdx.y;
    int t = threadIdx.x;
    int lane = t & 63, wave = t >> 6;
    int wr = wave >> 1, wc = wave & 1;
    f32x4 acc[4][4] = {};

    const u16* gA = A + (size_t)(bm * 128) * K;
    const u16* gB = BT + (size_t)(bn * 128) * K;

    auto stage = [&](int buf, int k0) {
#pragma unroll
        for (int i = 0; i < 2; i++) {
            int o = i * 4096 + t * 16;
            int row = o >> 6;
            int cb = (o & 63) ^ (((row >> 1) & 3) << 4);
            gload16(gA + (size_t)row * K + k0 + (cb >> 1),
                    &SMEM[buf * 4096 + i * 2048 + (t & 192) * 8]);
        }
#pragma unroll
        for (int i = 0; i < 2; i++) {
            int o = i * 4096 + t * 16;
            int row = o >> 6;
            int cb = (o & 63) ^ (((row >> 1) & 3) << 4);
            gload16(gB + (size_t)row * K + k0 + (cb >> 1),
                    &SMEM[12288 + buf * 4096 + i * 2048 + (t & 192) * 8]);
        }
    };

    stage(0, 0);
    stage(1, 32);
    WAITV(4);
    __builtin_amdgcn_s_barrier();

    for (int tt = 0; tt < 32; tt++) {
        bool pre = (tt + 2 < 32);
        if (pre) stage((tt + 2) % 3, (tt + 2) << 5);
        int row16 = lane & 15;
        int colb = ((lane >> 4) * 16) ^ (((row16 >> 1) & 3) << 4);
        const u16* Ab = &SMEM[(tt % 3) * 4096];
        const u16* Bb = &SMEM[12288 + (tt % 3) * 4096];
        short8 af[4], bf[4];
#pragma unroll
        for (int m = 0; m < 4; m++)
            af[m] = *(const short8*)&Ab[(wr * 64 + m * 16 + row16) * 32 + (colb >> 1)];
#pragma unroll
        for (int n = 0; n < 4; n++)
            bf[n] = *(const short8*)&Bb[(wc * 64 + n * 16 + row16) * 32 + (colb >> 1)];
        __builtin_amdgcn_s_setprio(1);
#pragma unroll
        for (int m = 0; m < 4; m++)
#pragma unroll
            for (int n = 0; n < 4; n++)
                acc[m][n] = __builtin_amdgcn_mfma_f32_16x16x32_bf16(
                    af[m], bf[n], acc[m][n], 0, 0, 0);
        __builtin_amdgcn_s_setprio(0);
        if (pre) { WAITV(4); } else { WAITV(0); }
        __builtin_amdgcn_s_barrier();
    }

    int l15 = lane & 15, hi = lane >> 4;
    if (bn < 8) {
        // ---- Q: straight rows into qbuf [4096][1024] ----
#pragma unroll
        for (int m = 0; m < 4; m++)
#pragma unroll
            for (int n = 0; n < 4; n++) {
                int col = bn * 128 + wc * 64 + n * 16 + l15;
                float bv = bias[col];
#pragma unroll
                for (int r = 0; r < 4; r++) {
                    int row = bm * 128 + wr * 64 + m * 16 + hi * 4 + r;
                    qbuf[(size_t)row * 1024 + col] = f2bf(acc[m][n][r] + bv);
                }
            }
    } else if (bn < 16) {
        // ---- K: packed kvp[bh][tt][0][k][d] ----
        int h2 = (bn - 8) * 2 + wc;     // head (wave-uniform)
#pragma unroll
        for (int m = 0; m < 4; m++)
#pragma unroll
            for (int n = 0; n < 4; n++) {
                int d = n * 16 + l15;
                float bv = bias[1024 + h2 * 64 + d];
#pragma unroll
                for (int r = 0; r < 4; r++) {
                    int row = bm * 128 + wr * 64 + m * 16 + hi * 4 + r;
                    int b = row >> 11;
                    int tt = (row & 2047) >> 6;
                    int k = row & 63;
                    kvp[(size_t)(b * 16 + h2) * 262144 + tt * 8192 + k * 64 + d] =
                        f2bf(acc[m][n][r] + bv);
                }
            }
    } else {
        // ---- V: transpose via per-wave LDS, packed kvp[bh][tt][1][d][k] ----
        int h2 = (bn - 16) * 2 + wc;
        int rowbase = bm * 128 + wr * 64;
        int b = rowbase >> 11;
        int tt = (rowbase & 2047) >> 6;
        u16* wl = &SMEM[wave * 4608];   // 64 x stride-72, post-barrier reuse
#pragma unroll
        for (int m = 0; m < 4; m++)
#pragma unroll
            for (int n = 0; n < 4; n++) {
                int d = n * 16 + l15;
                float bv = bias[2048 + h2 * 64 + d];
                unsigned p0 = cvtpk(acc[m][n][0] + bv, acc[m][n][1] + bv);
                unsigned p1 = cvtpk(acc[m][n][2] + bv, acc[m][n][3] + bv);
                *(uint2v*)&wl[d * 72 + m * 16 + hi * 4] = (uint2v){p0, p1};
            }
        u16* dst = kvp + (size_t)(b * 16 + h2) * 262144 + tt * 8192 + 4096;
#pragma unroll
        for (int i = 0; i < 8; i++)
            *(uint4v*)(dst + lane * 64 + i * 8) = *(const uint4v*)&wl[lane * 72 + i * 8];
    }
}

// ------- gemm2: attnb @ Wo^T + bo (BN=64, counted-vmcnt, swizzled) --------
__global__ __launch_bounds__(256) void gemm_out(
    const u16* __restrict__ A, const u16* __restrict__ BT,
    const float* __restrict__ bias, float* __restrict__ Cout) {
    const int K = 1024, N = 1024;
    __shared__ __align__(16) u16 As[3][4096];
    __shared__ __align__(16) u16 Bs[3][2048];
    int bm = blockIdx.x, bn = blockIdx.y;
    int t = threadIdx.x;
    int lane = t & 63, wave = t >> 6;
    int wr = wave >> 1, wc = wave & 1;
    f32x4 acc[4][2] = {};

    const u16* gA = A + (size_t)(bm * 128) * K;
    const u16* gB = BT + (size_t)(bn * 64) * K;

    auto stage = [&](int buf, int k0) {
#pragma unroll
        for (int i = 0; i < 2; i++) {
            int o = i * 4096 + t * 16;
            int row = o >> 6;
            int cb = (o & 63) ^ (((row >> 1) & 3) << 4);
            gload16(gA + (size_t)row * K + k0 + (cb >> 1),
                    &As[buf][i * 2048 + (t & 192) * 8]);
        }
        {
            int o = t * 16;
            int row = o >> 6;
            int cb = (o & 63) ^ (((row >> 1) & 3) << 4);
            gload16(gB + (size_t)row * K + k0 + (cb >> 1),
                    &Bs[buf][(t & 192) * 8]);
        }
    };

    stage(0, 0);
    stage(1, 32);
    WAITV(3);
    __builtin_amdgcn_s_barrier();

    for (int tt = 0; tt < 32; tt++) {
        bool pre = (tt + 2 < 32);
        if (pre) stage((tt + 2) % 3, (tt + 2) << 5);
        int row16 = lane & 15;
        int colb = ((lane >> 4) * 16) ^ (((row16 >> 1) & 3) << 4);
        short8 af[4], bf[2];
#pragma unroll
        for (int m = 0; m < 4; m++)
            af[m] = *(const short8*)&As[tt % 3][(wr * 64 + m * 16 + row16) * 32 + (colb >> 1)];
#pragma unroll
        for (int n = 0; n < 2; n++)
            bf[n] = *(const short8*)&Bs[tt % 3][(wc * 32 + n * 16 + row16) * 32 + (colb >> 1)];
        __builtin_amdgcn_s_setprio(1);
#pragma unroll
        for (int m = 0; m < 4; m++)
#pragma unroll
            for (int n = 0; n < 2; n++)
                acc[m][n] = __builtin_amdgcn_mfma_f32_16x16x32_bf16(
                    af[m], bf[n], acc[m][n], 0, 0, 0);
        __builtin_amdgcn_s_setprio(0);
        if (pre) { WAITV(3); } else { WAITV(0); }
        __builtin_amdgcn_s_barrier();
    }

#pragma unroll
    for (int m = 0; m < 4; m++)
#pragma unroll
        for (int n = 0; n < 2; n++) {
            int col = bn * 64 + wc * 32 + n * 16 + (lane & 15);
            float bv = bias[col];
#pragma unroll
            for (int r = 0; r < 4; r++) {
                int row = bm * 128 + wr * 64 + m * 16 + (lane >> 4) * 4 + r;
                Cout[(size_t)row * N + col] = acc[m][n][r] + bv;
            }
        }
}

// ------- causal flash attention v13 = v12 minus sched_barrier fences ------
__global__ __launch_bounds__(256, 2) void attn_kernel(
    const u16* __restrict__ qbuf, const u16* __restrict__ kvp,
    u16* __restrict__ attn, float* __restrict__ part_o,
    float* __restrict__ part_l) {
    int bid = blockIdx.x;
    int bh = bid & 31;
    int j = 23 - (bid >> 5);             // heavy (j>=8) first
    int sp, tbeg, tend, kc = 0;
    bool partial;
    if (j >= 8) {
        int idx = j - 8;                 // 0..15
        sp = 8 + (idx >> 1);
        kc = idx & 1;
        int half = sp + 1;
        partial = true;
        tbeg = kc ? half : 0;
        tend = kc ? 2 * sp + 2 : half;
    } else {
        sp = j;
        partial = false;
        tbeg = 0;
        tend = 2 * sp + 2;
    }
    int b = bh >> 4, h = bh & 15;
    int t = threadIdx.x;
    int lane = t & 63, w = t >> 6;
    int qb = sp * 128 + w * 32;
    int kend = qb + 32;
    int l31 = lane & 31, hi32 = lane >> 5;
    int swz = (lane & 7) << 4;

    __shared__ __align__(16) u16 KVb[24576];   // [3 bufs][K 4096 | V 4096]

    const u16* kvb = kvp + (size_t)bh * 262144;

    auto stage = [&](int buf, int tt) {
        const char* g0 = (const char*)(kvb + (size_t)tt * 8192);
#pragma unroll
        for (int kv2 = 0; kv2 < 2; kv2++)
#pragma unroll
            for (int i = 0; i < 2; i++) {
                int o = i * 4096 + t * 16;
                int row = o >> 7;
                int cb = (o & 127) ^ ((row & 7) << 4);
                gload16((const u16*)(g0 + kv2 * 8192 + row * 128 + cb),
                        &KVb[buf * 8192 + kv2 * 4096 + i * 2048 + (t & 192) * 8]);
            }
    };

    short8 qf[4];
    {
        const u16* q0 = qbuf + (size_t)(b * 2048 + qb + l31) * 1024 + h * 64 + hi32 * 8;
#pragma unroll
        for (int dd = 0; dd < 4; dd++) qf[dd] = *(const short8*)(q0 + dd * 16);
    }
    stage(tbeg % 3, tbeg);
    stage((tbeg + 1) % 3, tbeg + 1);

    float l_lane = 0.f;
    f32x16 oT[2] = {};

    const float C1 = 0.1803368880f;    // 0.125/ln2
    const float C2 = -17.3123404907f;  // 12/ln2

    WAITV(4);
    __builtin_amdgcn_s_barrier();

    for (int tt = tbeg; tt < tend; tt++) {
        bool pre = (tt + 2 < tend);
        if (pre) stage((tt + 2) % 3, tt + 2);
        int k0 = tt * 64;
        if (k0 < kend) {
            const u16* Ks = &KVb[(tt % 3) * 8192];
            const u16* Vs = Ks + 4096;
            f32x16 sc[2];
            __builtin_amdgcn_s_setprio(1);
#pragma unroll
            for (int kb = 0; kb < 2; kb++) {
                f32x16 z = {};
#pragma unroll
                for (int dd = 0; dd < 4; dd++) {
                    int off = (kb * 32 + l31) * 64 + (((dd * 32 + hi32 * 16) ^ swz) >> 1);
                    short8 kf = *(const short8*)&Ks[off];
                    z = __builtin_amdgcn_mfma_f32_32x32x16_bf16(kf, qf[dd], z, 0, 0, 0);
                }
                sc[kb] = z;
            }
            __builtin_amdgcn_s_setprio(0);

            float p[2][16];
            int q_g = qb + l31;
            if (k0 + 64 > qb) {
#pragma unroll
                for (int kb = 0; kb < 2; kb++)
#pragma unroll
                    for (int r = 0; r < 16; r++) {
                        int kg = k0 + kb * 32 + (r & 3) + 8 * (r >> 2) + 4 * hi32;
                        float v = (kg <= q_g) ? sc[kb][r] : -1e30f;
                        float pe = __builtin_amdgcn_exp2f(fmaf(v, C1, C2));
                        p[kb][r] = pe;
                        l_lane += pe;
                    }
            } else {
#pragma unroll
                for (int kb = 0; kb < 2; kb++)
#pragma unroll
                    for (int r = 0; r < 16; r++) {
                        float pe = __builtin_amdgcn_exp2f(fmaf(sc[kb][r], C1, C2));
                        p[kb][r] = pe;
                        l_lane += pe;
                    }
            }

            short8 pb[4];
#pragma unroll
            for (int kb = 0; kb < 2; kb++)
#pragma unroll
                for (int cset = 0; cset < 2; cset++) {
                    const float* pp = &p[kb][cset * 8];
                    unsigned A0 = cvtpk(pp[0], pp[1]);
                    unsigned A1 = cvtpk(pp[2], pp[3]);
                    unsigned A2 = cvtpk(pp[4], pp[5]);
                    unsigned A3 = cvtpk(pp[6], pp[7]);
                    unsigned za = hi32 ? A0 : A2;
                    unsigned zb = hi32 ? A1 : A3;
                    unsigned sa = (unsigned)__shfl_xor((int)za, 32, 64);
                    unsigned sb = (unsigned)__shfl_xor((int)zb, 32, 64);
                    uint4v wv;
                    wv[0] = hi32 ? sa : A0;
                    wv[1] = hi32 ? sb : A1;
                    wv[2] = hi32 ? A2 : sa;
                    wv[3] = hi32 ? A3 : sb;
                    pb[kb * 2 + cset] = __builtin_bit_cast(short8, wv);
                }

            __builtin_amdgcn_s_setprio(1);
#pragma unroll
            for (int mb = 0; mb < 2; mb++)
#pragma unroll
                for (int kk = 0; kk < 4; kk++) {
                    int off = (mb * 32 + l31) * 64 + (((kk * 32 + hi32 * 16) ^ swz) >> 1);
                    short8 vf = *(const short8*)&Vs[off];
                    oT[mb] = __builtin_amdgcn_mfma_f32_32x32x16_bf16(vf, pb[kk], oT[mb], 0, 0, 0);
                }
            __builtin_amdgcn_s_setprio(0);
        }
        if (pre) { WAITV(4); } else { WAITV(0); }
        __builtin_amdgcn_s_barrier();
    }

    if (partial) {
        int blk = (bh * 8 + (sp - 8)) * 2 + kc;
        float* po = part_o + (size_t)blk * 8192;
        int lr = w * 32 + l31;
        float lf = l_lane + __shfl_xor(l_lane, 32, 64);
        if (hi32 == 0) part_l[blk * 128 + lr] = lf;
#pragma unroll
        for (int mb = 0; mb < 2; mb++)
#pragma unroll
            for (int r = 0; r < 16; r++) {
                int d = mb * 32 + (r & 3) + 8 * (r >> 2) + 4 * hi32;
                po[lr * 64 + d] = oT[mb][r];
            }
        return;
    }

    float lf = l_lane + __shfl_xor(l_lane, 32, 64);
    float linv = __builtin_amdgcn_rcpf(lf);
    u16* gp = attn + (size_t)(b * 2048 + qb + l31) * 1024 + h * 64;
#pragma unroll
    for (int mb = 0; mb < 2; mb++)
#pragma unroll
        for (int g = 0; g < 4; g++) {
            unsigned w0 = cvtpk(oT[mb][4 * g] * linv, oT[mb][4 * g + 1] * linv);
            unsigned w1 = cvtpk(oT[mb][4 * g + 2] * linv, oT[mb][4 * g + 3] * linv);
            int d0 = mb * 32 + g * 8 + hi32 * 4;
            *(uint2v*)(gp + d0) = (uint2v){w0, w1};
        }
}

// ---- merge split-K partials: out = (o0+o1)/(l0+l1), bf16 ----
__global__ __launch_bounds__(256) void attn_merge(
    const float* __restrict__ part_o, const float* __restrict__ part_l,
    u16* __restrict__ attn) {
    int bid = blockIdx.x;
    int bh = bid & 31;
    int sp8 = bid >> 5;                  // 0..7
    int sp = sp8 + 8;
    int b = bh >> 4, h = bh & 15;
    int t = threadIdx.x;
    int blk0 = (bh * 8 + sp8) * 2;
    const float* o0 = part_o + (size_t)blk0 * 8192;
    const float* o1 = o0 + 8192;
    const float* l0 = part_l + blk0 * 128;
    const float* l1 = l0 + 128;
#pragma unroll
    for (int i = 0; i < 4; i++) {
        int r = (t >> 3) + i * 32;
        int d0 = (t & 7) * 8;
        float linv = __builtin_amdgcn_rcpf(l0[r] + l1[r]);
        const float* a = o0 + r * 64 + d0;
        const float* c = o1 + r * 64 + d0;
        uint4v w;
#pragma unroll
        for (int k = 0; k < 4; k++)
            w[k] = cvtpk((a[2 * k] + c[2 * k]) * linv,
                         (a[2 * k + 1] + c[2 * k + 1]) * linv);
        u16* gp = attn + (size_t)(b * 2048 + sp * 128 + r) * 1024 + h * 64 + d0;
        *(uint4v*)gp = w;
    }
}

extern "C" void kernel_launch(void* const* d_in, const int* in_sizes, int n_in,
                              void* d_out, int out_size, void* d_ws, size_t ws_size,
                              hipStream_t stream) {
    const float* x    = (const float*)d_in[0];
    const float* Wqkv = (const float*)d_in[1];
    const float* bqkv = (const float*)d_in[2];
    const float* Wo   = (const float*)d_in[3];
    const float* bo   = (const float*)d_in[4];
    float* out = (float*)d_out;

    char* ws = (char*)d_ws;
    u16* x_bf   = (u16*)(ws);                     //  8 MB (attnb reuses after)
    u16* attnb  = (u16*)(ws);                     //  8 MB
    u16* wqkvT  = (u16*)(ws + (8ull << 20));      //  6 MB
    u16* woT    = (u16*)(ws + (14ull << 20));     //  2 MB
    u16* qbuf   = (u16*)(ws + (16ull << 20));     //  8 MB: [4096][1024]
    u16* kvp    = (u16*)(ws + (24ull << 20));     // 16 MB: [32][32][2][64][64]
    float* part_o = (float*)(ws + (40ull << 20)); // 16 MB: [512][8192]
    float* part_l = (float*)(ws + (56ull << 20)); // 256 KB

    prep<<<3072, 256, 0, stream>>>(x, Wqkv, Wo, x_bf, wqkvT, woT);
    gemm_qkv<<<dim3(32, 24), 256, 0, stream>>>(x_bf, wqkvT, bqkv, qbuf, kvp);
    attn_kernel<<<768, 256, 0, stream>>>(qbuf, kvp, attnb, part_o, part_l);
    attn_merge<<<256, 256, 0, stream>>>(part_o, part_l, attnb);
    gemm_out<<<dim3(32, 16), 256, 0, stream>>>(attnb, woT, bo, out);
}